// Round 9
// baseline (211.071 us; speedup 1.0000x reference)
//
#include <hip/hip_runtime.h>
#include <math.h>

#define T_LEN 512
#define H_DIM 50
#define BPB   16          // batches per block (MFMA N)
#define NW    13          // waves per block = one real 16-row tile each
#define L2E   1.44269504088896f
#define XSTR  520         // halves per x-row (512 + pad so [512] stays in-bounds)

typedef _Float16 half8_t __attribute__((ext_vector_type(8)));
typedef float    f32x4_t __attribute__((ext_vector_type(4)));

// Device-guarded: host pass lacks the builtin (round-5 lesson).
__device__ __forceinline__ f32x4_t mfma16(half8_t a, half8_t b, f32x4_t c) {
#if defined(__HIP_DEVICE_COMPILE__)
    return __builtin_amdgcn_mfma_f32_16x16x32_f16(a, b, c, 0, 0, 0);
#else
    return c;
#endif
}
// cvt_pkrtz returns __fp16x2 -> bit_cast immediately (round-7 lesson).
__device__ __forceinline__ int pk16(float a, float b) {
    return __builtin_bit_cast(int, __builtin_amdgcn_cvt_pkrtz(a, b));
}
__device__ __forceinline__ float sigm(float v) {
    return __builtin_amdgcn_rcpf(1.0f + __builtin_amdgcn_exp2f(v * (-L2E)));
}
__device__ __forceinline__ float tanh_f(float v) {
    return __fmaf_rn(
        __builtin_amdgcn_rcpf(1.0f + __builtin_amdgcn_exp2f(v * (-2.0f * L2E))),
        2.0f, -1.0f);
}

// Block = 832 threads = 13 waves = 16 batch elements, whole recurrence.
// gates[208 x 16] = W'[208 x 64] . H'[64 x 16]; wave w owns exactly ONE
// 16-row tile (rows 16w..16w+15, perm p = 4*unit + gate) -> no fake tiles,
// minimal per-wave load, 13 waves/CU for latency overlap.
// vs round 8: (a) h layout hb[buf][unit-block][batch][8] makes every
// B-fragment ds_read_b128 a contiguous 1KB wave read (ZERO bank conflicts,
// 16B aligned) — round 8 had 1.19e7 conflict cycles from the 44-dword col
// stride; (b) bias rides in the MFMA C operand (D!=C), killing the per-step
// zero4 init and the k=51 column; (c) K aug: k<50 = W_hh, k=50 = x_t slot.
__global__ __launch_bounds__(NW * 64, 1) void lstm_mfma(
    const float* __restrict__ x,
    const float* __restrict__ W_ih,
    const float* __restrict__ W_hh,
    const float* __restrict__ b_ih,
    const float* __restrict__ b_hh,
    const float* __restrict__ W_fc,
    const float* __restrict__ b_fc,
    float* __restrict__ out)
{
    const int tid = threadIdx.x;
    const int w   = tid >> 6;        // wave = tile index 0..12
    const int L   = tid & 63;
    const int col = L & 15;          // batch-in-block == A-row == D-col
    const int g4  = L >> 4;          // lane group 0..3

    __shared__ _Float16 xls[BPB][XSTR];
    __shared__ __align__(16) _Float16 hb[2][8][BPB][8];  // [buf][u>>3][batch][u&7]

    // ---- stage x (16 batches x 512) f32 -> f16
    {
        const float4* xg4 = reinterpret_cast<const float4*>(
            x + (size_t)blockIdx.x * BPB * T_LEN);
        for (int f = tid; f < BPB * T_LEN / 4; f += NW * 64) {
            const float4 v = xg4[f];
            const int bb = f >> 7;               // 128 float4 per batch row
            const int c0 = (f & 127) << 2;
            *reinterpret_cast<int*>(&xls[bb][c0])     = pk16(v.x, v.y);
            *reinterpret_cast<int*>(&xls[bb][c0 + 2]) = pk16(v.z, v.w);
        }
    }
    // ---- zero both h buffers (2*8*16*8 halves = 1024 dwords)
    for (int i = tid; i < 1024; i += NW * 64) reinterpret_cast<int*>(hb)[i] = 0;
    __syncthreads();
    if (tid < BPB) hb[0][6][tid][2] = xls[tid][0];   // x_0 lives at k=50 slot

    // ---- one-time A-fragment load: A-row = col -> perm p = 16w+col
    const int pA = 16 * w + col;
    const int uA = pA >> 2, gA = pA & 3;
    half8_t a0, a1;
    #pragma unroll
    for (int j = 0; j < 8; ++j) {
        const int k0 = 8 * g4 + j;               // kc=0: k in [0,32) -> W_hh
        const int k1 = 32 + k0;                  // kc=1: k in [32,64)
        float v0 = 0.0f, v1 = 0.0f;
        if (uA < H_DIM) {
            const int r = gA * H_DIM + uA;       // torch row: gate*50 + unit
            v0 = W_hh[r * H_DIM + k0];
            if (k1 < H_DIM)       v1 = W_hh[r * H_DIM + k1];
            else if (k1 == H_DIM) v1 = W_ih[r];  // k=50: x slot
        }
        a0[j] = (_Float16)v0;
        a1[j] = (_Float16)v1;
    }

    // ---- D-side: lane owns unit uD = 4w+g4, gates = acc[0..3]
    const int uD  = 4 * w + g4;
    const bool wr = (uD < H_DIM);
    f32x4_t biasC;
    #pragma unroll
    for (int j = 0; j < 4; ++j)
        biasC[j] = wr ? (b_ih[j * H_DIM + uD] + b_hh[j * H_DIM + uD]) : 0.0f;
    const int wrblk = uD >> 3, wrslot = uD & 7;
    const bool xw = (w == 12) && (g4 == 3);      // masked-out lanes do x duty

    float c = 0.0f;
    __syncthreads();

    #pragma unroll 2
    for (int t = 0; t < T_LEN; ++t) {
        const int cur = t & 1, nxt = cur ^ 1;
        // B-fragments: contiguous 16B per lane, 1KB per wave, conflict-free
        const half8_t b0 = *reinterpret_cast<const half8_t*>(&hb[cur][g4][col][0]);
        const half8_t b1 = *reinterpret_cast<const half8_t*>(&hb[cur][4 + g4][col][0]);

        f32x4_t acc = mfma16(a0, b0, biasC);     // C = bias (D != C, no init)
        acc = mfma16(a1, b1, acc);

        // acc = (i,f,g,o) of unit uD, batch col — lane-local cell update
        const float ig = sigm(acc[0]);
        const float fg = sigm(acc[1]);
        const float gt = tanh_f(acc[2]);
        const float og = sigm(acc[3]);
        c = __fmaf_rn(fg, c, ig * gt);
        const float hv = og * tanh_f(c);
        if (wr) hb[nxt][wrblk][col][wrslot] = (_Float16)hv;
        if (xw) hb[nxt][6][col][2] = xls[col][t + 1];  // t=511 -> pad, never read
        __syncthreads();
    }

    // ---- epilogue: h_512 is in hb[0]; out[b] = h . W_fc + b_fc
    if (w == 0) {
        float part = 0.0f;
        #pragma unroll
        for (int j = 0; j < 13; ++j) {
            const int u = 13 * g4 + j;
            if (u < H_DIM)
                part += (float)hb[0][u >> 3][col][u & 7] * W_fc[u];
        }
        part += __shfl_xor(part, 16);
        part += __shfl_xor(part, 32);
        if (L < BPB) out[blockIdx.x * BPB + L] = part + b_fc[0];
    }
}

extern "C" void kernel_launch(void* const* d_in, const int* in_sizes, int n_in,
                              void* d_out, int out_size, void* d_ws, size_t ws_size,
                              hipStream_t stream) {
    const float* x    = (const float*)d_in[0];
    const float* W_ih = (const float*)d_in[1];
    const float* W_hh = (const float*)d_in[2];
    const float* b_ih = (const float*)d_in[3];
    const float* b_hh = (const float*)d_in[4];
    const float* W_fc = (const float*)d_in[5];
    const float* b_fc = (const float*)d_in[6];
    float* out = (float*)d_out;

    const int B = in_sizes[0] / T_LEN;   // 4096
    lstm_mfma<<<dim3(B / BPB), dim3(NW * 64), 0, stream>>>(
        x, W_ih, W_hh, b_ih, b_hh, W_fc, b_fc, out);
}

// Round 10
// 200.058 us; speedup vs baseline: 1.0550x; 1.0550x over previous
//
#include <hip/hip_runtime.h>
#include <math.h>

#define T_LEN 512
#define H_DIM 50
#define BPB   16          // batches per block (MFMA N)
#define NW    13          // waves per block = one real 16-row tile each
#define L2E   1.44269504088896f
#define XSTR  520         // halves per x-row (512 + pad so [512] stays in-bounds)

typedef _Float16 half8_t __attribute__((ext_vector_type(8)));
typedef float    f32x4_t __attribute__((ext_vector_type(4)));

// Device-guarded: host pass lacks the builtin (round-5 lesson).
__device__ __forceinline__ f32x4_t mfma16(half8_t a, half8_t b, f32x4_t c) {
#if defined(__HIP_DEVICE_COMPILE__)
    return __builtin_amdgcn_mfma_f32_16x16x32_f16(a, b, c, 0, 0, 0);
#else
    return c;
#endif
}
// cvt_pkrtz returns __fp16x2 -> bit_cast immediately (round-7 lesson).
__device__ __forceinline__ int pk16(float a, float b) {
    return __builtin_bit_cast(int, __builtin_amdgcn_cvt_pkrtz(a, b));
}
__device__ __forceinline__ float sigm(float v) {
    return __builtin_amdgcn_rcpf(1.0f + __builtin_amdgcn_exp2f(v * (-L2E)));
}
__device__ __forceinline__ float tanh_f(float v) {
    return __fmaf_rn(
        __builtin_amdgcn_rcpf(1.0f + __builtin_amdgcn_exp2f(v * (-2.0f * L2E))),
        2.0f, -1.0f);
}

// Block = 832 threads = 13 waves = 16 batch elements, whole recurrence.
// gates[208 x 16] = W'[208 x 64] . H'[64 x 16] per step; wave w owns ONE
// 16-row tile (rows perm p = 4*unit + gate -> lane-local cell update).
// h layout hb[buf][u>>3][batch][u&7]: B-fragment reads are contiguous 1KB
// wave reads (conflict-free). Bias rides the MFMA C operand. K aug: k=50
// carries x_t (one wave feeds it). vs round 9: hand-unrolled x2 so ALL
// in-loop LDS accesses are constant offsets from precomputed per-lane
// pointers (round 9 spent ~25% of issue on hb[cur] address recompute);
// x-feed value prefetched at step top (hides its LDS latency); branchless
// h-write (fakes land in zero-weighted k=52/53 slots).
__global__ __launch_bounds__(NW * 64, 1) void lstm_mfma(
    const float* __restrict__ x,
    const float* __restrict__ W_ih,
    const float* __restrict__ W_hh,
    const float* __restrict__ b_ih,
    const float* __restrict__ b_hh,
    const float* __restrict__ W_fc,
    const float* __restrict__ b_fc,
    float* __restrict__ out)
{
    const int tid = threadIdx.x;
    const int w   = tid >> 6;        // wave = tile index 0..12
    const int L   = tid & 63;
    const int col = L & 15;          // batch-in-block == A-row == D-col
    const int g4  = L >> 4;          // lane group 0..3

    __shared__ _Float16 xls[BPB][XSTR];
    __shared__ __align__(16) _Float16 hb[2][8][BPB][8];  // [buf][u>>3][batch][u&7]

    // ---- stage x (16 batches x 512) f32 -> f16
    {
        const float4* xg4 = reinterpret_cast<const float4*>(
            x + (size_t)blockIdx.x * BPB * T_LEN);
        for (int f = tid; f < BPB * T_LEN / 4; f += NW * 64) {
            const float4 v = xg4[f];
            const int bb = f >> 7;               // 128 float4 per batch row
            const int c0 = (f & 127) << 2;
            *reinterpret_cast<int*>(&xls[bb][c0])     = pk16(v.x, v.y);
            *reinterpret_cast<int*>(&xls[bb][c0 + 2]) = pk16(v.z, v.w);
        }
    }
    // ---- zero both h buffers (2*8*16*8 halves = 1024 dwords)
    for (int i = tid; i < 1024; i += NW * 64) reinterpret_cast<int*>(hb)[i] = 0;
    __syncthreads();
    if (tid < BPB) hb[0][6][tid][2] = xls[tid][0];   // x_0 lives at k=50 slot

    // ---- one-time A-fragment load: A-row = col -> perm p = 16w+col
    const int pA = 16 * w + col;
    const int uA = pA >> 2, gA = pA & 3;
    half8_t a0, a1;
    #pragma unroll
    for (int j = 0; j < 8; ++j) {
        const int k0 = 8 * g4 + j;               // kc=0: k in [0,32) -> W_hh
        const int k1 = 32 + k0;                  // kc=1: k in [32,64)
        float v0 = 0.0f, v1 = 0.0f;
        if (uA < H_DIM) {
            const int r = gA * H_DIM + uA;       // torch row: gate*50 + unit
            v0 = W_hh[r * H_DIM + k0];
            if (k1 < H_DIM)       v1 = W_hh[r * H_DIM + k1];
            else if (k1 == H_DIM) v1 = W_ih[r];  // k=50: x slot
        }
        a0[j] = (_Float16)v0;
        a1[j] = (_Float16)v1;
    }

    // ---- D-side: lane owns unit uD = 4w+g4, gates = acc[0..3]
    const int uD  = 4 * w + g4;
    const bool wr = (uD < H_DIM);
    f32x4_t biasC;
    #pragma unroll
    for (int j = 0; j < 4; ++j)
        biasC[j] = wr ? (b_ih[j * H_DIM + uD] + b_hh[j * H_DIM + uD]) : 0.0f;

    // Precomputed pointers; in-loop accesses are CONSTANT offsets from these.
    const int uDw = wr ? uD : (52 + (uD & 1));   // fakes -> k=52/53 (zero-weight)
    _Float16* hw = &hb[0][uDw >> 3][col][uDw & 7];
    const _Float16* rB = &hb[0][0][0][0] + (g4 * 128 + col * 8);
    const _Float16* xq = &xls[col][1];
    _Float16* xd = &hb[0][6][col][2];            // x slot (k=50), buffer 0
    const bool xw = (w == 12) && (g4 == 3);      // x-feed duty: fake-heavy wave

    float c = 0.0f;
    __syncthreads();

    // RO/WO = half-offsets for read/write buffer; XI = x index within pair.
    auto step = [&](int RO, int WO, int XI) {
        const half8_t b0 = *reinterpret_cast<const half8_t*>(rB + RO);
        const half8_t b1 = *reinterpret_cast<const half8_t*>(rB + RO + 512);
        _Float16 xn = (_Float16)0.0f;
        if (xw) xn = xq[XI];                     // prefetch: consumed ~200cyc later
        f32x4_t acc = mfma16(a0, b0, biasC);     // C = bias (D != C, no init)
        acc = mfma16(a1, b1, acc);
        const float ig = sigm(acc[0]);
        const float fg = sigm(acc[1]);
        const float gt = tanh_f(acc[2]);
        const float og = sigm(acc[3]);
        c = __fmaf_rn(fg, c, ig * gt);
        const float hv = og * tanh_f(c);
        hw[WO] = (_Float16)hv;                   // branchless (fakes: zero-weight slot)
        if (xw) xd[WO] = xn;
        __syncthreads();
    };

    for (int t = 0; t < T_LEN; t += 2) {
        step(0,    1024, 0);                     // even: read buf0, write buf1
        step(1024, 0,    1);                     // odd:  read buf1, write buf0
        xq += 2;
    }

    // ---- epilogue: h_512 is in hb[0]; out[b] = h . W_fc + b_fc
    if (w == 0) {
        float part = 0.0f;
        #pragma unroll
        for (int j = 0; j < 13; ++j) {
            const int u = 13 * g4 + j;
            if (u < H_DIM)
                part += (float)hb[0][u >> 3][col][u & 7] * W_fc[u];
        }
        part += __shfl_xor(part, 16);
        part += __shfl_xor(part, 32);
        if (L < BPB) out[blockIdx.x * BPB + L] = part + b_fc[0];
    }
}

extern "C" void kernel_launch(void* const* d_in, const int* in_sizes, int n_in,
                              void* d_out, int out_size, void* d_ws, size_t ws_size,
                              hipStream_t stream) {
    const float* x    = (const float*)d_in[0];
    const float* W_ih = (const float*)d_in[1];
    const float* W_hh = (const float*)d_in[2];
    const float* b_ih = (const float*)d_in[3];
    const float* b_hh = (const float*)d_in[4];
    const float* W_fc = (const float*)d_in[5];
    const float* b_fc = (const float*)d_in[6];
    float* out = (float*)d_out;

    const int B = in_sizes[0] / T_LEN;   // 4096
    lstm_mfma<<<dim3(B / BPB), dim3(NW * 64), 0, stream>>>(
        x, W_ih, W_hh, b_ih, b_hh, W_fc, b_fc, out);
}

// Round 11
// 190.255 us; speedup vs baseline: 1.1094x; 1.0515x over previous
//
#include <hip/hip_runtime.h>
#include <math.h>

#define T_LEN 512
#define H_DIM 50
#define BPB   16          // batches per block (MFMA N)
#define NW    13          // waves per block = one real 16-row tile each
#define L2E   1.44269504088896f
#define XSTR  520         // halves per x-row (512 + pad so [512..515] stay in-bounds)

typedef _Float16 half8_t __attribute__((ext_vector_type(8)));
typedef float    f32x4_t __attribute__((ext_vector_type(4)));

// Device-guarded: host pass lacks the builtin (round-5 lesson).
__device__ __forceinline__ f32x4_t mfma16(half8_t a, half8_t b, f32x4_t c) {
#if defined(__HIP_DEVICE_COMPILE__)
    return __builtin_amdgcn_mfma_f32_16x16x32_f16(a, b, c, 0, 0, 0);
#else
    return c;
#endif
}
// cvt_pkrtz returns __fp16x2 -> bit_cast immediately (round-7 lesson).
__device__ __forceinline__ int pk16(float a, float b) {
    return __builtin_bit_cast(int, __builtin_amdgcn_cvt_pkrtz(a, b));
}

// Block = 832 threads = 13 waves = 16 batch elements, whole recurrence.
// gates[208 x 16] = W'[208 x 64] . H'[64 x 16] per step; wave w owns ONE
// 16-row tile (rows perm p = 4*unit + gate -> lane-local cell update).
// h layout hb[buf][u>>3][batch][u&7]: B-fragment reads are contiguous 1KB
// wave reads (conflict-free). Bias rides the MFMA C operand; k=50 carries x.
// vs round 10 (issue-shaving round; SIMD0 carries 4/13 waves = the wall):
// (a) W'/bias PRE-SCALED by -log2e (-2log2e for g-rows) so MFMA emits
//     exp2-ready pre-acts -> 4 fewer v_mul per lane-step;
// (b) x-feed duty moved off SIMD0 (wave 12 -> wave 9 under i%4 mapping);
// (c) t-loop unrolled x4 (2 buffer pairs) to amortize loop overhead.
__global__ __launch_bounds__(NW * 64, 1) void lstm_mfma(
    const float* __restrict__ x,
    const float* __restrict__ W_ih,
    const float* __restrict__ W_hh,
    const float* __restrict__ b_ih,
    const float* __restrict__ b_hh,
    const float* __restrict__ W_fc,
    const float* __restrict__ b_fc,
    float* __restrict__ out)
{
    const int tid = threadIdx.x;
    const int w   = tid >> 6;        // wave = tile index 0..12
    const int L   = tid & 63;
    const int col = L & 15;          // batch-in-block == D-col
    const int g4  = L >> 4;          // lane group 0..3

    __shared__ _Float16 xls[BPB][XSTR];
    __shared__ __align__(16) _Float16 hb[2][8][BPB][8];  // [buf][u>>3][batch][u&7]

    // ---- stage x (16 batches x 512) f32 -> f16
    {
        const float4* xg4 = reinterpret_cast<const float4*>(
            x + (size_t)blockIdx.x * BPB * T_LEN);
        for (int f = tid; f < BPB * T_LEN / 4; f += NW * 64) {
            const float4 v = xg4[f];
            const int bb = f >> 7;               // 128 float4 per batch row
            const int c0 = (f & 127) << 2;
            *reinterpret_cast<int*>(&xls[bb][c0])     = pk16(v.x, v.y);
            *reinterpret_cast<int*>(&xls[bb][c0 + 2]) = pk16(v.z, v.w);
        }
    }
    // ---- zero both h buffers (2*8*16*8 halves = 1024 dwords)
    for (int i = tid; i < 1024; i += NW * 64) reinterpret_cast<int*>(hb)[i] = 0;
    __syncthreads();
    if (tid < BPB) hb[0][6][tid][2] = xls[tid][0];   // x_0 lives at k=50 slot

    // ---- one-time A-fragment load: A-row = col -> perm p = 16w+col
    // Rows pre-scaled: gate rows i,f,o by -L2E; g rows by -2*L2E, so the MFMA
    // output feeds exp2 directly (activation domain).
    const int pA = 16 * w + col;
    const int uA = pA >> 2, gA = pA & 3;
    const float sA = (gA == 2) ? (-2.0f * L2E) : (-L2E);
    half8_t a0, a1;
    #pragma unroll
    for (int j = 0; j < 8; ++j) {
        const int k0 = 8 * g4 + j;               // kc=0: k in [0,32) -> W_hh
        const int k1 = 32 + k0;                  // kc=1: k in [32,64)
        float v0 = 0.0f, v1 = 0.0f;
        if (uA < H_DIM) {
            const int r = gA * H_DIM + uA;       // torch row: gate*50 + unit
            v0 = W_hh[r * H_DIM + k0];
            if (k1 < H_DIM)       v1 = W_hh[r * H_DIM + k1];
            else if (k1 == H_DIM) v1 = W_ih[r];  // k=50: x slot
        }
        a0[j] = (_Float16)(v0 * sA);
        a1[j] = (_Float16)(v1 * sA);
    }

    // ---- D-side: lane owns unit uD = 4w+g4, gates = acc[0..3] (pre-scaled)
    const int uD  = 4 * w + g4;
    const bool wr = (uD < H_DIM);
    f32x4_t biasC;
    #pragma unroll
    for (int j = 0; j < 4; ++j) {
        const float sj = (j == 2) ? (-2.0f * L2E) : (-L2E);
        biasC[j] = wr ? (b_ih[j * H_DIM + uD] + b_hh[j * H_DIM + uD]) * sj : 0.0f;
    }

    // Precomputed pointers; in-loop accesses are CONSTANT offsets from these.
    const int uDw = wr ? uD : (52 + (uD & 1));   // fakes -> k=52/53 (zero-weight)
    _Float16* hw = &hb[0][uDw >> 3][col][uDw & 7];
    const _Float16* rB = &hb[0][0][0][0] + (g4 * 128 + col * 8);
    const _Float16* xq = &xls[col][1];
    _Float16* xd = &hb[0][6][col][2];            // x slot (k=50), buffer 0
    const bool xw = (w == 9) && (g4 == 3);       // x-feed duty: OFF SIMD0 (i%4)

    float c = 0.0f;
    __syncthreads();

    // RO/WO = half-offsets for read/write buffer; XI = x index within quad.
    auto step = [&](int RO, int WO, int XI) {
        const half8_t b0 = *reinterpret_cast<const half8_t*>(rB + RO);
        const half8_t b1 = *reinterpret_cast<const half8_t*>(rB + RO + 512);
        _Float16 xn = (_Float16)0.0f;
        if (xw) xn = xq[XI];                     // prefetch: consumed ~200cyc later
        f32x4_t acc = mfma16(a0, b0, biasC);     // C = bias (D != C, no init)
        acc = mfma16(a1, b1, acc);
        // acc already in exp2 domain (pre-scaled rows)
        const float ig = __builtin_amdgcn_rcpf(1.0f + __builtin_amdgcn_exp2f(acc[0]));
        const float fg = __builtin_amdgcn_rcpf(1.0f + __builtin_amdgcn_exp2f(acc[1]));
        const float g2 = __builtin_amdgcn_rcpf(1.0f + __builtin_amdgcn_exp2f(acc[2]));
        const float og = __builtin_amdgcn_rcpf(1.0f + __builtin_amdgcn_exp2f(acc[3]));
        const float gt = __fmaf_rn(g2, 2.0f, -1.0f);
        c = __fmaf_rn(fg, c, ig * gt);
        const float et = __builtin_amdgcn_exp2f(c * (-2.0f * L2E));
        const float tc = __fmaf_rn(__builtin_amdgcn_rcpf(1.0f + et), 2.0f, -1.0f);
        const float hv = og * tc;
        hw[WO] = (_Float16)hv;                   // branchless (fakes: zero-weight slot)
        if (xw) xd[WO] = xn;
        __syncthreads();
    };

    for (int t = 0; t < T_LEN; t += 4) {         // 2 buffer pairs per iter
        step(0,    1024, 0);                     // read buf0, write buf1
        step(1024, 0,    1);
        step(0,    1024, 2);
        step(1024, 0,    3);
        xq += 4;
    }

    // ---- epilogue: h_512 is in hb[0]; out[b] = h . W_fc + b_fc
    if (w == 0) {
        float part = 0.0f;
        #pragma unroll
        for (int j = 0; j < 13; ++j) {
            const int u = 13 * g4 + j;
            if (u < H_DIM)
                part += (float)hb[0][u >> 3][col][u & 7] * W_fc[u];
        }
        part += __shfl_xor(part, 16);
        part += __shfl_xor(part, 32);
        if (L < BPB) out[blockIdx.x * BPB + L] = part + b_fc[0];
    }
}

extern "C" void kernel_launch(void* const* d_in, const int* in_sizes, int n_in,
                              void* d_out, int out_size, void* d_ws, size_t ws_size,
                              hipStream_t stream) {
    const float* x    = (const float*)d_in[0];
    const float* W_ih = (const float*)d_in[1];
    const float* W_hh = (const float*)d_in[2];
    const float* b_ih = (const float*)d_in[3];
    const float* b_hh = (const float*)d_in[4];
    const float* W_fc = (const float*)d_in[5];
    const float* b_fc = (const float*)d_in[6];
    float* out = (float*)d_out;

    const int B = in_sizes[0] / T_LEN;   // 4096
    lstm_mfma<<<dim3(B / BPB), dim3(NW * 64), 0, stream>>>(
        x, W_ih, W_hh, b_ih, b_hh, W_fc, b_fc, out);
}